// Round 14
// baseline (606.413 us; speedup 1.0000x reference)
//
#include <hip/hip_runtime.h>

// ---------------- types ----------------
typedef __bf16 bf16x8 __attribute__((ext_vector_type(8)));
typedef float f32x4 __attribute__((ext_vector_type(4)));

__device__ __forceinline__ unsigned short f2bf(float f) {
    unsigned int u = __builtin_bit_cast(unsigned int, f);
    u += 0x7FFFu + ((u >> 16) & 1u);
    return (unsigned short)(u >> 16);
}

// ---------------- weight f32 -> bf16 conversion ----------------
__global__ void cvt_kernel(const float* __restrict__ in,
                           unsigned short* __restrict__ out, long n4) {
    long i = (long)blockIdx.x * blockDim.x + threadIdx.x;
    long stride = (long)gridDim.x * blockDim.x;
    for (; i < n4; i += stride) {
        float4 v = ((const float4*)in)[i];
        ushort4 o;
        o.x = f2bf(v.x); o.y = f2bf(v.y); o.z = f2bf(v.z); o.w = f2bf(v.w);
        ((ushort4*)out)[i] = o;
    }
}

// ---------------- fused 2-token attention -> h0 (bf16) ----------------
__global__ __launch_bounds__(256) void attn_kernel(
    const float* __restrict__ x1, const float* __restrict__ x2,
    unsigned short* __restrict__ h) {
    const int D = 1024;
    const int lane = threadIdx.x & 63;
    const int wave = threadIdx.x >> 6;
    const long row = (long)blockIdx.x * 4 + wave;
    const float4* p1 = (const float4*)(x1 + row * D);
    const float4* p2 = (const float4*)(x2 + row * D);
    float4 v1[4], v2[4];
    float s11 = 0.f, s12 = 0.f, s22 = 0.f;
#pragma unroll
    for (int j = 0; j < 4; ++j) {
        v1[j] = p1[lane + 64 * j];
        v2[j] = p2[lane + 64 * j];
        s11 += v1[j].x * v1[j].x + v1[j].y * v1[j].y + v1[j].z * v1[j].z + v1[j].w * v1[j].w;
        s12 += v1[j].x * v2[j].x + v1[j].y * v2[j].y + v1[j].z * v2[j].z + v1[j].w * v2[j].w;
        s22 += v2[j].x * v2[j].x + v2[j].y * v2[j].y + v2[j].z * v2[j].z + v2[j].w * v2[j].w;
    }
#pragma unroll
    for (int off = 1; off < 64; off <<= 1) {
        s11 += __shfl_xor(s11, off);
        s12 += __shfl_xor(s12, off);
        s22 += __shfl_xor(s22, off);
    }
    const float a00 = 1.f / (1.f + expf((s12 - s11) * (1.f / 32.f)));
    const float a10 = 1.f / (1.f + expf((s22 - s12) * (1.f / 32.f)));
    const float a01 = 1.f - a00, a11 = 1.f - a10;
    unsigned short* h0 = h + row * 2048;
#pragma unroll
    for (int j = 0; j < 4; ++j) {
        const int f = lane + 64 * j;
        ushort4 o0, o1;
        o0.x = f2bf(a00 * v1[j].x + a01 * v2[j].x);
        o0.y = f2bf(a00 * v1[j].y + a01 * v2[j].y);
        o0.z = f2bf(a00 * v1[j].z + a01 * v2[j].z);
        o0.w = f2bf(a00 * v1[j].w + a01 * v2[j].w);
        o1.x = f2bf(a10 * v1[j].x + a11 * v2[j].x);
        o1.y = f2bf(a10 * v1[j].y + a11 * v2[j].y);
        o1.z = f2bf(a10 * v1[j].z + a11 * v2[j].z);
        o1.w = f2bf(a10 * v1[j].w + a11 * v2[j].w);
        ((ushort4*)(h0))[f] = o0;
        ((ushort4*)(h0 + 1024))[f] = o1;
    }
}

// ------------- 256x256 GEMM: port/pipe-overlapped 1-barrier phases ---------
// R13 rotation (8x16KiB K-split regions, 1 stage/phase, st_16x32 swizzle,
// XCD M-ownership) + EARLY fragment reads: each region issues the NEXT
// phase's ds_reads (ping-pong Bf0/Bf1 per kh, Af0/Af1 per phase) alongside
// the CURRENT MFMA cluster -> LDS port drains under the matrix pipe.
// Compiler inserts counted lgkmcnt via register deps (no manual LGKM0).
// VMW(6): stage retired at age 3, published by that phase's BAR; earliest
// read is age 4 -> race-free (ledger walked for all 8 regions + tail).
#define BAR   __builtin_amdgcn_s_barrier()
#define VMW(n) asm volatile("s_waitcnt vmcnt(" #n ")" ::: "memory")

#define MMQ(mb, BS, AS)                                                        \
  _Pragma("unroll") for (int n = 0; n < 4; ++n)                                \
  _Pragma("unroll") for (int mq = 0; mq < 4; ++mq)                             \
    acc[(mb) + mq][n] = __builtin_amdgcn_mfma_f32_16x16x32_bf16(               \
        BS[n], AS[mq], acc[(mb) + mq][n], 0, 0, 0);

template <bool RELU, typename OT>
__global__ __launch_bounds__(512, 1) void gemm256(
    const unsigned short* __restrict__ A,   // [M,K] bf16 (activations)
    const unsigned short* __restrict__ Bw,  // [N,K] bf16 (weights)
    const float* __restrict__ bias,         // [N]
    OT* __restrict__ C,                     // [M,N]
    int N, int K) {
    __shared__ __align__(16) unsigned short lds[65536];  // 128 KiB
    const int tid = threadIdx.x;
    const int lane = tid & 63, wave = tid >> 6;
    const int wm = wave >> 2, wn = wave & 3;
    const int fr = lane & 15, fq = lane >> 4;

    // XCD M-ownership swizzle (R12: FETCH 270->98 MB)
    const int nbn = N >> 8;
    const int sh = (nbn == 8) ? 3 : 2;
    const int cpx = (int)gridDim.x >> 3;
    const int swz = ((int)blockIdx.x & 7) * cpx + ((int)blockIdx.x >> 3);
    const int bn = swz & (nbn - 1);
    const int bm = swz >> sh;
    const long m0 = (long)bm * 256, n0 = (long)bn * 256;
    const long rowb = (long)K * 2;

    // read addressing: region + row*64 + (fq*16 ^ st_16x32 flip)
    const int flip = ((fr >> 3) & 1) << 5;
    const int lbase = fr * 64 + ((fq * 16) ^ flip);
    const int aRd = wm * 8192 + lbase;           // + mh*4096 + mq*1024
    const int bRd = 32768 + wn * 4096 + lbase;   // + nf*1024
    const char* ldsc = (const char*)lds;

    // stage addressing (linear LDS dest, pre-swizzled global source)
    const int srow = wave * 16 + (lane >> 2);              // + L*128
    const int scol = ((lane & 3) << 4) ^ ((lane >> 5) << 5);
    const char* Abl = (const char*)A + m0 * rowb;
    const char* Bbl = (const char*)Bw + n0 * rowb;

    auto stage = [&](const char* mb, int regbase, int kh, int kt) {
#pragma unroll
        for (int L = 0; L < 2; ++L) {
            const int r = L * 128 + srow;
            const char* src = mb + (long)r * rowb + kt * 128 + kh * 64 + scol;
            __builtin_amdgcn_global_load_lds(
                (const __attribute__((address_space(1))) void*)src,
                (__attribute__((address_space(3))) void*)((char*)lds +
                    (regbase + kh * 16384 + L * 8192 + wave * 1024)),
                16, 0, 0);
        }
    };

    f32x4 acc[8][4] = {};
    bf16x8 Bf0[4], Bf1[4], Af0[4], Af1[4];

    auto rdB = [&](int Tb, int kh, bf16x8 (&D)[4]) {
        const int b = Tb + kh * 16384 + bRd;
#pragma unroll
        for (int nf = 0; nf < 4; ++nf)
            D[nf] = *(const bf16x8*)(ldsc + b + nf * 1024);
    };
    auto rdA = [&](int Tb, int kh, int mh, bf16x8 (&D)[4]) {
        const int b = Tb + kh * 16384 + aRd + mh * 4096;
#pragma unroll
        for (int mq = 0; mq < 4; ++mq)
            D[mq] = *(const bf16x8*)(ldsc + b + mq * 1024);
    };

    // ---- prologue: S0 all 4 (t0), S1.{B,A}.kh0 (t1); retire t0.kh0; F1 ----
    stage(Bbl, 32768, 0, 0);          // pro1 S0.B.kh0
    stage(Abl, 0,     0, 0);          // pro2 S0.A.kh0
    stage(Bbl, 32768, 1, 0);          // pro3 S0.B.kh1
    stage(Abl, 0,     1, 0);          // pro4 S0.A.kh1
    stage(Bbl, 65536 + 32768, 0, 1);  // pro5 S1.B.kh0
    stage(Abl, 65536,         0, 1);  // pro6 S1.A.kh0
    VMW(8);
    BAR;
    rdB(0, 0, Bf0); rdA(0, 0, 0, Af0);   // P1 frags

    const int NT = K >> 6, NIT = NT >> 1;
    for (int i = 0; i < NIT - 1; ++i) {
        const int u = 2 * i + 1, t2 = 2 * i + 2, t3 = 2 * i + 3;
        // P1: cur (Bf0,Af0); early S0.kh0.mh1 -> Af1
        stage(Bbl, 65536 + 32768, 1, u);
        rdA(0, 0, 1, Af1);
        MMQ(0, Bf0, Af0);
        VMW(6); BAR;
        // P2: cur (Bf0,Af1); early S0.kh1 -> Bf1, Af0
        stage(Abl, 65536, 1, u);
        rdB(0, 1, Bf1); rdA(0, 1, 0, Af0);
        MMQ(4, Bf0, Af1);
        VMW(6); BAR;
        // P3: cur (Bf1,Af0); early S0.kh1.mh1 -> Af1
        stage(Bbl, 32768, 0, t2);
        rdA(0, 1, 1, Af1);
        MMQ(0, Bf1, Af0);
        VMW(6); BAR;
        // P4: cur (Bf1,Af1); early S1.kh0 -> Bf0, Af0
        stage(Abl, 0, 0, t2);
        rdB(65536, 0, Bf0); rdA(65536, 0, 0, Af0);
        MMQ(4, Bf1, Af1);
        VMW(6); BAR;
        // P5: cur (Bf0,Af0); early S1.kh0.mh1 -> Af1
        stage(Bbl, 32768, 1, t2);
        rdA(65536, 0, 1, Af1);
        MMQ(0, Bf0, Af0);
        VMW(6); BAR;
        // P6: cur (Bf0,Af1); early S1.kh1 -> Bf1, Af0
        stage(Abl, 0, 1, t2);
        rdB(65536, 1, Bf1); rdA(65536, 1, 0, Af0);
        MMQ(4, Bf0, Af1);
        VMW(6); BAR;
        // P7: cur (Bf1,Af0); early S1.kh1.mh1 -> Af1
        stage(Bbl, 65536 + 32768, 0, t3);
        rdA(65536, 1, 1, Af1);
        MMQ(0, Bf1, Af0);
        VMW(6); BAR;
        // P8: cur (Bf1,Af1); early S0.kh0 (next tile pair) -> Bf0, Af0
        stage(Abl, 65536, 0, t3);
        rdB(0, 0, Bf0); rdA(0, 0, 0, Af0);
        MMQ(4, Bf1, Af1);
        VMW(6); BAR;
    }
    {   // ---- tail iteration: stages P3..P8 off; VMW cascade 6,6,4,2,0 ----
        const int u = NT - 1;
        stage(Bbl, 65536 + 32768, 1, u);
        rdA(0, 0, 1, Af1);
        MMQ(0, Bf0, Af0);
        VMW(6); BAR;
        stage(Abl, 65536, 1, u);
        rdB(0, 1, Bf1); rdA(0, 1, 0, Af0);
        MMQ(4, Bf0, Af1);
        VMW(6); BAR;
        rdA(0, 1, 1, Af1);
        MMQ(0, Bf1, Af0);
        VMW(4); BAR;
        rdB(65536, 0, Bf0); rdA(65536, 0, 0, Af0);
        MMQ(4, Bf1, Af1);
        VMW(2); BAR;
        rdA(65536, 0, 1, Af1);
        MMQ(0, Bf0, Af0);
        VMW(0); BAR;
        rdB(65536, 1, Bf1); rdA(65536, 1, 0, Af0);
        MMQ(4, Bf0, Af1);
        BAR;
        rdA(65536, 1, 1, Af1);
        MMQ(0, Bf1, Af0);
        BAR;
        MMQ(4, Bf1, Af1);
    }

    // ---- epilogue: swapped layout => lane owns row (fr) x 4 consecutive cols
    const long crow0 = m0 + wm * 128 + fr;
    const long ccol0 = n0 + wn * 64 + fq * 4;
    float4 bv[4];
#pragma unroll
    for (int n = 0; n < 4; ++n) bv[n] = *(const float4*)(bias + ccol0 + n * 16);
#pragma unroll
    for (int m = 0; m < 8; ++m) {
        const long rb = (crow0 + m * 16) * N;
#pragma unroll
        for (int n = 0; n < 4; ++n) {
            float v0 = acc[m][n][0] + bv[n].x;
            float v1 = acc[m][n][1] + bv[n].y;
            float v2 = acc[m][n][2] + bv[n].z;
            float v3 = acc[m][n][3] + bv[n].w;
            if (RELU) {
                v0 = v0 > 0.f ? v0 : 0.f; v1 = v1 > 0.f ? v1 : 0.f;
                v2 = v2 > 0.f ? v2 : 0.f; v3 = v3 > 0.f ? v3 : 0.f;
            }
            if constexpr (sizeof(OT) == 2) {
                uint2 oo;
                oo.x = (unsigned)f2bf(v0) | ((unsigned)f2bf(v1) << 16);
                oo.y = (unsigned)f2bf(v2) | ((unsigned)f2bf(v3) << 16);
                *(uint2*)((unsigned short*)C + rb + ccol0 + n * 16) = oo;
            } else {
                *(float4*)((float*)C + rb + ccol0 + n * 16) =
                    make_float4(v0, v1, v2, v3);
            }
        }
    }
}

// ---------------- launch ----------------
extern "C" void kernel_launch(void* const* d_in, const int* in_sizes, int n_in,
                              void* d_out, int out_size, void* d_ws, size_t ws_size,
                              hipStream_t stream) {
    const float* x1 = (const float*)d_in[0];
    const float* x2 = (const float*)d_in[1];
    const float* Ws = (const float*)d_in[2];   // [4,2048,2048]
    const float* bs = (const float*)d_in[3];   // [4,2048]
    const float* Wl = (const float*)d_in[4];   // [1024,2048]
    const float* bl = (const float*)d_in[5];   // [1024]
    float* out = (float*)d_out;                // [16384,1024]

    char* ws = (char*)d_ws;
    unsigned short* hA  = (unsigned short*)(ws);                  // 64 MiB
    unsigned short* hB  = (unsigned short*)(ws + (67108864L));    // 64 MiB
    unsigned short* Wbf = (unsigned short*)(ws + (134217728L));   // 32 MiB
    unsigned short* Wlb = (unsigned short*)(ws + (167772160L));   // 4 MiB

    cvt_kernel<<<2048, 256, 0, stream>>>(Ws, Wbf, 4L * 2048 * 2048 / 4);
    cvt_kernel<<<512, 256, 0, stream>>>(Wl, Wlb, 1024L * 2048 / 4);

    attn_kernel<<<16384 / 4, 256, 0, stream>>>(x1, x2, hA);

    // MLP: 4x relu GEMM (bf16 ping-pong) + final GEMM (f32 out)
    gemm256<true, unsigned short><<<512, 512, 0, stream>>>(hA, Wbf + 0L * 2048 * 2048, bs + 0 * 2048, hB, 2048, 2048);
    gemm256<true, unsigned short><<<512, 512, 0, stream>>>(hB, Wbf + 1L * 2048 * 2048, bs + 1 * 2048, hA, 2048, 2048);
    gemm256<true, unsigned short><<<512, 512, 0, stream>>>(hA, Wbf + 2L * 2048 * 2048, bs + 2 * 2048, hB, 2048, 2048);
    gemm256<true, unsigned short><<<512, 512, 0, stream>>>(hB, Wbf + 3L * 2048 * 2048, bs + 3 * 2048, hA, 2048, 2048);
    gemm256<false, float><<<256, 512, 0, stream>>>(hA, Wlb, bl, out, 1024, 2048);
}

// Round 15
// 597.151 us; speedup vs baseline: 1.0155x; 1.0155x over previous
//
#include <hip/hip_runtime.h>

// ---------------- types ----------------
typedef __bf16 bf16x8 __attribute__((ext_vector_type(8)));
typedef float f32x4 __attribute__((ext_vector_type(4)));

__device__ __forceinline__ unsigned short f2bf(float f) {
    unsigned int u = __builtin_bit_cast(unsigned int, f);
    u += 0x7FFFu + ((u >> 16) & 1u);
    return (unsigned short)(u >> 16);
}

// ---------------- weight f32 -> bf16 conversion ----------------
__global__ void cvt_kernel(const float* __restrict__ in,
                           unsigned short* __restrict__ out, long n4) {
    long i = (long)blockIdx.x * blockDim.x + threadIdx.x;
    long stride = (long)gridDim.x * blockDim.x;
    for (; i < n4; i += stride) {
        float4 v = ((const float4*)in)[i];
        ushort4 o;
        o.x = f2bf(v.x); o.y = f2bf(v.y); o.z = f2bf(v.z); o.w = f2bf(v.w);
        ((ushort4*)out)[i] = o;
    }
}

// ---------------- fused 2-token attention -> h0 (bf16) ----------------
__global__ __launch_bounds__(256) void attn_kernel(
    const float* __restrict__ x1, const float* __restrict__ x2,
    unsigned short* __restrict__ h) {
    const int D = 1024;
    const int lane = threadIdx.x & 63;
    const int wave = threadIdx.x >> 6;
    const long row = (long)blockIdx.x * 4 + wave;
    const float4* p1 = (const float4*)(x1 + row * D);
    const float4* p2 = (const float4*)(x2 + row * D);
    float4 v1[4], v2[4];
    float s11 = 0.f, s12 = 0.f, s22 = 0.f;
#pragma unroll
    for (int j = 0; j < 4; ++j) {
        v1[j] = p1[lane + 64 * j];
        v2[j] = p2[lane + 64 * j];
        s11 += v1[j].x * v1[j].x + v1[j].y * v1[j].y + v1[j].z * v1[j].z + v1[j].w * v1[j].w;
        s12 += v1[j].x * v2[j].x + v1[j].y * v2[j].y + v1[j].z * v2[j].z + v1[j].w * v2[j].w;
        s22 += v2[j].x * v2[j].x + v2[j].y * v2[j].y + v2[j].z * v2[j].z + v2[j].w * v2[j].w;
    }
#pragma unroll
    for (int off = 1; off < 64; off <<= 1) {
        s11 += __shfl_xor(s11, off);
        s12 += __shfl_xor(s12, off);
        s22 += __shfl_xor(s22, off);
    }
    const float a00 = 1.f / (1.f + expf((s12 - s11) * (1.f / 32.f)));
    const float a10 = 1.f / (1.f + expf((s22 - s12) * (1.f / 32.f)));
    const float a01 = 1.f - a00, a11 = 1.f - a10;
    unsigned short* h0 = h + row * 2048;
#pragma unroll
    for (int j = 0; j < 4; ++j) {
        const int f = lane + 64 * j;
        ushort4 o0, o1;
        o0.x = f2bf(a00 * v1[j].x + a01 * v2[j].x);
        o0.y = f2bf(a00 * v1[j].y + a01 * v2[j].y);
        o0.z = f2bf(a00 * v1[j].z + a01 * v2[j].z);
        o0.w = f2bf(a00 * v1[j].w + a01 * v2[j].w);
        o1.x = f2bf(a10 * v1[j].x + a11 * v2[j].x);
        o1.y = f2bf(a10 * v1[j].y + a11 * v2[j].y);
        o1.z = f2bf(a10 * v1[j].z + a11 * v2[j].z);
        o1.w = f2bf(a10 * v1[j].w + a11 * v2[j].w);
        ((ushort4*)(h0))[f] = o0;
        ((ushort4*)(h0 + 1024))[f] = o1;
    }
}

// ------------- 256x256 GEMM, 1-stage/1-barrier phases + T5 setprio ---------
// R13 structure verbatim (8x16KiB K-split regions, 1 stage/phase, st_16x32
// swizzle, XCD M-ownership, counted VMW(8) before single barrier) with
// s_setprio(1) around each MFMA cluster: CU scheduler prefers the
// MFMA-issuing wave, so the co-resident wave's ds_reads/stages fill the
// MFMA issue bubbles -> cross-wave port/pipe overlap (T5/m218b regime).
#define BAR   __builtin_amdgcn_s_barrier()
#define LGKM0 do { asm volatile("s_waitcnt lgkmcnt(0)" ::: "memory"); \
                   __builtin_amdgcn_sched_barrier(0); } while (0)
#define VMW(n) asm volatile("s_waitcnt vmcnt(" #n ")" ::: "memory")
#define PRIO1 __builtin_amdgcn_s_setprio(1)
#define PRIO0 __builtin_amdgcn_s_setprio(0)

#define MMQ(mb)                                                                \
  PRIO1;                                                                       \
  _Pragma("unroll") for (int n = 0; n < 4; ++n)                                \
  _Pragma("unroll") for (int mq = 0; mq < 4; ++mq)                             \
    acc[(mb) + mq][n] = __builtin_amdgcn_mfma_f32_16x16x32_bf16(               \
        Bf[n], Af[mq], acc[(mb) + mq][n], 0, 0, 0);                            \
  PRIO0;

template <bool RELU, typename OT>
__global__ __launch_bounds__(512, 2) void gemm256(
    const unsigned short* __restrict__ A,   // [M,K] bf16 (activations)
    const unsigned short* __restrict__ Bw,  // [N,K] bf16 (weights)
    const float* __restrict__ bias,         // [N]
    OT* __restrict__ C,                     // [M,N]
    int N, int K) {
    __shared__ __align__(16) unsigned short lds[65536];  // 128 KiB
    const int tid = threadIdx.x;
    const int lane = tid & 63, wave = tid >> 6;
    const int wm = wave >> 2, wn = wave & 3;
    const int fr = lane & 15, fq = lane >> 4;

    // XCD M-ownership swizzle (R12, proven: FETCH 270->98 MB)
    const int nbn = N >> 8;
    const int sh = (nbn == 8) ? 3 : 2;
    const int cpx = (int)gridDim.x >> 3;
    const int swz = ((int)blockIdx.x & 7) * cpx + ((int)blockIdx.x >> 3);
    const int bn = swz & (nbn - 1);
    const int bm = swz >> sh;
    const long m0 = (long)bm * 256, n0 = (long)bn * 256;
    const long rowb = (long)K * 2;

    // read addressing: region + row*64 + (fq*16 ^ st_16x32 flip)
    const int flip = ((fr >> 3) & 1) << 5;
    const int lbase = fr * 64 + ((fq * 16) ^ flip);
    const int aRd = wm * 8192 + lbase;           // + mh*4096 + mq*1024
    const int bRd = 32768 + wn * 4096 + lbase;   // + nf*1024
    const char* ldsc = (const char*)lds;

    // stage addressing (linear LDS dest, pre-swizzled global source)
    const int srow = wave * 16 + (lane >> 2);              // + L*128
    const int scol = ((lane & 3) << 4) ^ ((lane >> 5) << 5);
    const char* Abl = (const char*)A + m0 * rowb;
    const char* Bbl = (const char*)Bw + n0 * rowb;

    auto stage = [&](const char* mb, int regbase, int kh, int kt) {
#pragma unroll
        for (int L = 0; L < 2; ++L) {
            const int r = L * 128 + srow;
            const char* src = mb + (long)r * rowb + kt * 128 + kh * 64 + scol;
            __builtin_amdgcn_global_load_lds(
                (const __attribute__((address_space(1))) void*)src,
                (__attribute__((address_space(3))) void*)((char*)lds +
                    (regbase + kh * 16384 + L * 8192 + wave * 1024)),
                16, 0, 0);
        }
    };

    f32x4 acc[8][4] = {};
    bf16x8 Bf[4], Af[4];

    auto rdB = [&](int Tb, int kh) {
        const int b = Tb + kh * 16384 + bRd;
#pragma unroll
        for (int nf = 0; nf < 4; ++nf)
            Bf[nf] = *(const bf16x8*)(ldsc + b + nf * 1024);
    };
    auto rdA = [&](int Tb, int kh, int mh) {
        const int b = Tb + kh * 16384 + aRd + mh * 4096;
#pragma unroll
        for (int mq = 0; mq < 4; ++mq)
            Af[mq] = *(const bf16x8*)(ldsc + b + mq * 1024);
    };

    // ---- prologue: S0 all 4 (t0), S1.{B,A}.kh0 (t1) = 6 stage-pairs ----
    stage(Bbl, 32768, 0, 0);          // pro1 S0.B.kh0
    stage(Abl, 0,     0, 0);          // pro2 S0.A.kh0
    stage(Bbl, 32768, 1, 0);          // pro3 S0.B.kh1
    stage(Abl, 0,     1, 0);          // pro4 S0.A.kh1
    stage(Bbl, 65536 + 32768, 0, 1);  // pro5 S1.B.kh0
    stage(Abl, 65536,         0, 1);  // pro6 S1.A.kh0
    VMW(8);                           // retires pro1,pro2 (P1's reads)
    BAR;

    const int NT = K >> 6, NIT = NT >> 1;
    for (int i = 0; i < NIT - 1; ++i) {
        const int u = 2 * i + 1, t2 = 2 * i + 2, t3 = 2 * i + 3;
        // P1: stage S1.B.kh1<-u (last read 2 phases ago); read S0 kh0
        stage(Bbl, 65536 + 32768, 1, u);
        rdB(0, 0); rdA(0, 0, 0);
        VMW(8); BAR; LGKM0; MMQ(0);
        // P2: stage S1.A.kh1<-u; read S0 kh0 mh1
        stage(Abl, 65536, 1, u);
        rdA(0, 0, 1);
        VMW(8); BAR; LGKM0; MMQ(4);
        // P3: stage S0.B.kh0<-t2; read S0 kh1
        stage(Bbl, 32768, 0, t2);
        rdB(0, 1); rdA(0, 1, 0);
        VMW(8); BAR; LGKM0; MMQ(0);
        // P4: stage S0.A.kh0<-t2; read S0 kh1 mh1
        stage(Abl, 0, 0, t2);
        rdA(0, 1, 1);
        VMW(8); BAR; LGKM0; MMQ(4);
        // P5: stage S0.B.kh1<-t2; read S1 kh0
        stage(Bbl, 32768, 1, t2);
        rdB(65536, 0); rdA(65536, 0, 0);
        VMW(8); BAR; LGKM0; MMQ(0);
        // P6: stage S0.A.kh1<-t2; read S1 kh0 mh1
        stage(Abl, 0, 1, t2);
        rdA(65536, 0, 1);
        VMW(8); BAR; LGKM0; MMQ(4);
        // P7: stage S1.B.kh0<-t3; read S1 kh1
        stage(Bbl, 65536 + 32768, 0, t3);
        rdB(65536, 1); rdA(65536, 1, 0);
        VMW(8); BAR; LGKM0; MMQ(0);
        // P8: stage S1.A.kh0<-t3; read S1 kh1 mh1
        stage(Abl, 65536, 0, t3);
        rdA(65536, 1, 1);
        VMW(8); BAR; LGKM0; MMQ(4);
    }
    {   // ---- tail iteration (u = NT-1): stages P3..P8 skipped ----
        const int u = NT - 1;
        stage(Bbl, 65536 + 32768, 1, u);
        rdB(0, 0); rdA(0, 0, 0);
        VMW(8); BAR; LGKM0; MMQ(0);
        stage(Abl, 65536, 1, u);
        rdA(0, 0, 1);
        VMW(8); BAR; LGKM0; MMQ(4);
        rdB(0, 1); rdA(0, 1, 0);
        VMW(8); BAR; LGKM0; MMQ(0);
        rdA(0, 1, 1);
        VMW(4); BAR; LGKM0; MMQ(4);
        rdB(65536, 0); rdA(65536, 0, 0);
        VMW(4); BAR; LGKM0; MMQ(0);
        rdA(65536, 0, 1);
        VMW(0); BAR; LGKM0; MMQ(4);
        rdB(65536, 1); rdA(65536, 1, 0);
        VMW(0); BAR; LGKM0; MMQ(0);
        rdA(65536, 1, 1);
        VMW(0); BAR; LGKM0; MMQ(4);
    }

    // ---- epilogue: swapped layout => lane owns row (fr) x 4 consecutive cols
    const long crow0 = m0 + wm * 128 + fr;
    const long ccol0 = n0 + wn * 64 + fq * 4;
    float4 bv[4];
#pragma unroll
    for (int n = 0; n < 4; ++n) bv[n] = *(const float4*)(bias + ccol0 + n * 16);
#pragma unroll
    for (int m = 0; m < 8; ++m) {
        const long rb = (crow0 + m * 16) * N;
#pragma unroll
        for (int n = 0; n < 4; ++n) {
            float v0 = acc[m][n][0] + bv[n].x;
            float v1 = acc[m][n][1] + bv[n].y;
            float v2 = acc[m][n][2] + bv[n].z;
            float v3 = acc[m][n][3] + bv[n].w;
            if (RELU) {
                v0 = v0 > 0.f ? v0 : 0.f; v1 = v1 > 0.f ? v1 : 0.f;
                v2 = v2 > 0.f ? v2 : 0.f; v3 = v3 > 0.f ? v3 : 0.f;
            }
            if constexpr (sizeof(OT) == 2) {
                uint2 oo;
                oo.x = (unsigned)f2bf(v0) | ((unsigned)f2bf(v1) << 16);
                oo.y = (unsigned)f2bf(v2) | ((unsigned)f2bf(v3) << 16);
                *(uint2*)((unsigned short*)C + rb + ccol0 + n * 16) = oo;
            } else {
                *(float4*)((float*)C + rb + ccol0 + n * 16) =
                    make_float4(v0, v1, v2, v3);
            }
        }
    }
}

// ---------------- launch ----------------
extern "C" void kernel_launch(void* const* d_in, const int* in_sizes, int n_in,
                              void* d_out, int out_size, void* d_ws, size_t ws_size,
                              hipStream_t stream) {
    const float* x1 = (const float*)d_in[0];
    const float* x2 = (const float*)d_in[1];
    const float* Ws = (const float*)d_in[2];   // [4,2048,2048]
    const float* bs = (const float*)d_in[3];   // [4,2048]
    const float* Wl = (const float*)d_in[4];   // [1024,2048]
    const float* bl = (const float*)d_in[5];   // [1024]
    float* out = (float*)d_out;                // [16384,1024]

    char* ws = (char*)d_ws;
    unsigned short* hA  = (unsigned short*)(ws);                  // 64 MiB
    unsigned short* hB  = (unsigned short*)(ws + (67108864L));    // 64 MiB
    unsigned short* Wbf = (unsigned short*)(ws + (134217728L));   // 32 MiB
    unsigned short* Wlb = (unsigned short*)(ws + (167772160L));   // 4 MiB

    cvt_kernel<<<2048, 256, 0, stream>>>(Ws, Wbf, 4L * 2048 * 2048 / 4);
    cvt_kernel<<<512, 256, 0, stream>>>(Wl, Wlb, 1024L * 2048 / 4);

    attn_kernel<<<16384 / 4, 256, 0, stream>>>(x1, x2, hA);

    // MLP: 4x relu GEMM (bf16 ping-pong) + final GEMM (f32 out)
    gemm256<true, unsigned short><<<512, 512, 0, stream>>>(hA, Wbf + 0L * 2048 * 2048, bs + 0 * 2048, hB, 2048, 2048);
    gemm256<true, unsigned short><<<512, 512, 0, stream>>>(hB, Wbf + 1L * 2048 * 2048, bs + 1 * 2048, hA, 2048, 2048);
    gemm256<true, unsigned short><<<512, 512, 0, stream>>>(hA, Wbf + 2L * 2048 * 2048, bs + 2 * 2048, hB, 2048, 2048);
    gemm256<true, unsigned short><<<512, 512, 0, stream>>>(hB, Wbf + 3L * 2048 * 2048, bs + 3 * 2048, hA, 2048, 2048);
    gemm256<false, float><<<256, 512, 0, stream>>>(hA, Wlb, bl, out, 1024, 2048);
}